// Round 4
// baseline (666.370 us; speedup 1.0000x reference)
//
#include <hip/hip_runtime.h>

#define NN 100000
#define EE 1600000

typedef unsigned short ushortT;
typedef unsigned int uintT;
typedef __attribute__((ext_vector_type(4))) float f32x4;
typedef __attribute__((ext_vector_type(8))) short bf16x8;

__device__ inline float bf2f(ushortT b) {
    return __uint_as_float(((uintT)b) << 16);
}
__device__ inline ushortT f2bf(float f) {
    uintT u = __float_as_uint(f);
    u += 0x7FFFu + ((u >> 16) & 1u);  // RNE
    return (ushortT)(u >> 16);
}

// ---------------------------------------------------------------------------
// f32 -> bf16 bulk convert (x -> xb), grid-stride float4
// ---------------------------------------------------------------------------
__global__ __launch_bounds__(256) void cvt_kernel(const float* __restrict__ x,
                                                  ushortT* __restrict__ xb) {
    const int total = NN * 256 / 4;
    for (int i = blockIdx.x * 256 + threadIdx.x; i < total; i += gridDim.x * 256) {
        float4 v = ((const float4*)x)[i];
        ushort4 o;
        o.x = f2bf(v.x); o.y = f2bf(v.y); o.z = f2bf(v.z); o.w = f2bf(v.w);
        ((ushort4*)xb)[i] = o;
    }
}

// ---------------------------------------------------------------------------
// histogram of edges per (dst, rel)
// ---------------------------------------------------------------------------
__global__ __launch_bounds__(256) void count3_kernel(const int* __restrict__ edst,
                                                     const int* __restrict__ etyp,
                                                     int* __restrict__ cnt3) {
    int e = blockIdx.x * blockDim.x + threadIdx.x;
    if (e >= EE) return;
    int d = edst[e], r = etyp[e];
    if ((unsigned)d >= NN || (unsigned)r >= 3u) return;
    atomicAdd(&cnt3[d * 3 + r], 1);
}

// ---------------------------------------------------------------------------
// exclusive scan of node degrees: 1 block, 1024 thr
// ---------------------------------------------------------------------------
__global__ __launch_bounds__(1024) void scan_kernel(const int* __restrict__ cnt3,
                                                    int* __restrict__ row_ptr) {
    __shared__ int wpart[16];
    __shared__ int s_carry;
    const int tid = threadIdx.x;
    const int lane = tid & 63, wid = tid >> 6;
    if (tid == 0) s_carry = 0;
    __syncthreads();
    for (int base = 0; base < NN; base += 1024) {
        int n = base + tid;
        int d = 0;
        if (n < NN) d = cnt3[n * 3] + cnt3[n * 3 + 1] + cnt3[n * 3 + 2];
        int v = d;
#pragma unroll
        for (int off = 1; off < 64; off <<= 1) {
            int t = __shfl_up(v, off);
            if (lane >= off) v += t;
        }
        if (lane == 63) wpart[wid] = v;
        __syncthreads();
        if (wid == 0) {
            int p = (lane < 16) ? wpart[lane] : 0;
#pragma unroll
            for (int off = 1; off < 16; off <<= 1) {
                int t = __shfl_up(p, off);
                if (lane >= off) p += t;
            }
            if (lane < 16) wpart[lane] = p;
        }
        __syncthreads();
        int total = wpart[15];
        int wexcl = (wid == 0) ? 0 : wpart[wid - 1];
        int excl = s_carry + wexcl + (v - d);
        if (n < NN) row_ptr[n] = excl;
        __syncthreads();
        if (tid == 0) s_carry += total;
        __syncthreads();
    }
    if (tid == 0) row_ptr[NN] = s_carry;
}

// ---------------------------------------------------------------------------
// fill CSR edge list: elist[row_ptr[d] + cursor[d]++] = (src<<2)|rel
// ---------------------------------------------------------------------------
__global__ __launch_bounds__(256) void fill_kernel(const int* __restrict__ esrc,
                                                   const int* __restrict__ edst,
                                                   const int* __restrict__ etyp,
                                                   const int* __restrict__ row_ptr,
                                                   int* __restrict__ cursor,
                                                   uintT* __restrict__ elist) {
    int e = blockIdx.x * blockDim.x + threadIdx.x;
    if (e >= EE) return;
    int s = esrc[e], d = edst[e], r = etyp[e];
    if ((unsigned)s >= NN || (unsigned)d >= NN || (unsigned)r >= 3u) return;
    int pos = row_ptr[d] + atomicAdd(&cursor[d], 1);
    elist[pos] = ((uintT)s << 2) | (uintT)r;
}

// ---------------------------------------------------------------------------
// pack [W|root] into MFMA-fragment-ready bf16 layout
// ---------------------------------------------------------------------------
template <int K>
__global__ __launch_bounds__(256) void bpack_kernel(const float* __restrict__ W,
                                                    const float* __restrict__ root,
                                                    ushortT* __restrict__ Bpack) {
    constexpr int KB = K / 32;
    int idx = blockIdx.x * blockDim.x + threadIdx.x;
    if (idx >= 512 * K) return;
    int j = idx & 7;
    int l = (idx >> 3) & 63;
    int blk = idx >> 9;  // nblk*KB + kblk
    int kb = blk % KB, nblk = blk / KB;
    int k = kb * 32 + (l >> 4) * 8 + j;
    int m = nblk * 16 + (l & 15);
    float v;
    if (m < 384) {
        v = W[(((size_t)(m >> 7)) * K + k) * 128 + (m & 127)];
    } else {
        v = root[(size_t)k * 128 + (m - 384)];
    }
    Bpack[idx] = f2bf(v);
}

// ---------------------------------------------------------------------------
// bf16 MFMA GEMM: C[N,512](bf16) = A[N,K](bf16) @ B[K,512]
// 128x128 tile, 4 waves (2x2), BK=32, A in swizzled LDS, B fragment-packed
// ---------------------------------------------------------------------------
__device__ inline int swz_off(int r, int g) {  // ushort offset of 16B unit
    return r * 32 + ((g ^ ((r >> 1) & 3)) << 3);
}

template <int K>
__global__ __launch_bounds__(256) void gemm_mfma_kernel(const ushortT* __restrict__ A,
                                                        const ushortT* __restrict__ Bpack,
                                                        ushortT* __restrict__ C, int N) {
    constexpr int KB = K / 32;
    __shared__ ushortT As[128 * 32];  // 8 KB

    const int tid = threadIdx.x;
    const int lane = tid & 63;
    const int wid = tid >> 6;
    const int wr = wid >> 1, wc = wid & 1;
    const int bm = blockIdx.x * 128;
    const int bnblk = blockIdx.y * 8;

    const int st_r = tid >> 1;
    const int st_g0 = (tid & 1) * 2;

    f32x4 acc[4][4] = {};
    bf16x8 breg[4], bnext[4], stg[2];

    auto stage_load = [&](int k0, bf16x8* out) {
#pragma unroll
        for (int u = 0; u < 2; ++u) {
            int row = bm + st_r;
            bf16x8 val = {};
            if (row < N) val = *(const bf16x8*)&A[(size_t)row * K + k0 + (st_g0 + u) * 8];
            out[u] = val;
        }
    };
    auto stage_write = [&](const bf16x8* v) {
#pragma unroll
        for (int u = 0; u < 2; ++u)
            *(bf16x8*)&As[swz_off(st_r, st_g0 + u)] = v[u];
    };
    auto load_b = [&](int kblk, bf16x8* out) {
#pragma unroll
        for (int nb = 0; nb < 4; ++nb) {
            int nblk = bnblk + wc * 4 + nb;
            out[nb] = *(const bf16x8*)&Bpack[((size_t)(nblk * KB + kblk) * 64 + lane) * 8];
        }
    };

    stage_load(0, stg);
    stage_write(stg);
    load_b(0, breg);

    for (int kblk = 0; kblk < KB; ++kblk) {
        __syncthreads();
        bf16x8 afrag[4];
#pragma unroll
        for (int mb = 0; mb < 4; ++mb) {
            int fr = wr * 64 + mb * 16 + (lane & 15);
            afrag[mb] = *(const bf16x8*)&As[swz_off(fr, lane >> 4)];
        }
        if (kblk + 1 < KB) {
            stage_load((kblk + 1) * 32, stg);
            load_b(kblk + 1, bnext);
        }
#pragma unroll
        for (int mb = 0; mb < 4; ++mb)
#pragma unroll
            for (int nb = 0; nb < 4; ++nb)
                acc[mb][nb] = __builtin_amdgcn_mfma_f32_16x16x32_bf16(
                    afrag[mb], breg[nb], acc[mb][nb], 0, 0, 0);
        __syncthreads();
        if (kblk + 1 < KB) {
            stage_write(stg);
#pragma unroll
            for (int nb = 0; nb < 4; ++nb) breg[nb] = bnext[nb];
        }
    }

    // C/D layout: col=lane&15, row=(lane>>4)*4+q  [guide m89/m91]
#pragma unroll
    for (int mb = 0; mb < 4; ++mb) {
        int row0 = bm + wr * 64 + mb * 16 + ((lane >> 4) << 2);
#pragma unroll
        for (int nb = 0; nb < 4; ++nb) {
            int col = (bnblk + wc * 4 + nb) * 16 + (lane & 15);
#pragma unroll
            for (int q = 0; q < 4; ++q) {
                int row = row0 + q;
                if (row < N) C[(size_t)row * 512 + col] = f2bf(acc[mb][nb][q]);
            }
        }
    }
}

// ---------------------------------------------------------------------------
// fused CSR aggregation + root + bias + LN (+leaky / +LN2)
// 2 waves per node, half-wave edge split, ushort4/lane, 2x unroll.
// Block = 256 thr = 4 waves = 2 nodes. Grid = NN/2.
// ---------------------------------------------------------------------------
template <int LAYER>
__global__ __launch_bounds__(256) void agg_finalize_kernel(
    const ushortT* __restrict__ trans, const uintT* __restrict__ elist,
    const int* __restrict__ row_ptr, const int* __restrict__ cnt3,
    const float* __restrict__ bias, const float* __restrict__ gamma,
    const float* __restrict__ beta, const float* __restrict__ gout,
    const float* __restrict__ bout, void* __restrict__ outp) {
    __shared__ float part[2][128];
    const int tid = threadIdx.x;
    const int lane = tid & 63;
    const int wid = tid >> 6;   // 0..3
    const int nb = wid >> 1;    // node within block
    const int wp = wid & 1;     // wave within node pair
    const int half = lane >> 5;
    const int cb = (lane & 31) * 4;  // channel base (each lane: 4 channels)
    const int n = blockIdx.x * 2 + nb;

    const int start = row_ptr[n];
    const int end = row_ptr[n + 1];
    const float i0 = 1.0f / fmaxf((float)cnt3[n * 3 + 0], 1.0f);
    const float i1 = 1.0f / fmaxf((float)cnt3[n * 3 + 1], 1.0f);
    const float i2 = 1.0f / fmaxf((float)cnt3[n * 3 + 2], 1.0f);

    float a0 = 0.f, a1 = 0.f, a2 = 0.f, a3 = 0.f;
    // wave wp handles edges {start+wp*2+half, +4, +8, ...} in pairs
    for (int ib = start + wp * 2; ib < end; ib += 8) {
        int iA = ib + half;
        int iB = ib + 4 + half;
        ushort4 uA = {}, uB = {};
        float wA = 0.f, wB = 0.f;
        if (iA < end) {
            uintT ev = elist[iA];
            int s = ev >> 2, r = ev & 3;
            uA = *(const ushort4*)&trans[(size_t)s * 512 + r * 128 + cb];
            wA = r == 0 ? i0 : (r == 1 ? i1 : i2);
        }
        if (iB < end) {
            uintT ev = elist[iB];
            int s = ev >> 2, r = ev & 3;
            uB = *(const ushort4*)&trans[(size_t)s * 512 + r * 128 + cb];
            wB = r == 0 ? i0 : (r == 1 ? i1 : i2);
        }
        a0 += wA * bf2f(uA.x) + wB * bf2f(uB.x);
        a1 += wA * bf2f(uA.y) + wB * bf2f(uB.y);
        a2 += wA * bf2f(uA.z) + wB * bf2f(uB.z);
        a3 += wA * bf2f(uA.w) + wB * bf2f(uB.w);
    }
    // combine half-waves
    a0 += __shfl_xor(a0, 32);
    a1 += __shfl_xor(a1, 32);
    a2 += __shfl_xor(a2, 32);
    a3 += __shfl_xor(a3, 32);

    if (wp == 1 && lane < 32)
        *(float4*)&part[nb][cb] = make_float4(a0, a1, a2, a3);
    __syncthreads();
    if (wp == 1) return;

    float4 p = *(const float4*)&part[nb][cb];
    ushort4 rt = *(const ushort4*)&trans[(size_t)n * 512 + 384 + cb];
    float4 bi = *(const float4*)&bias[cb];
    float v0 = a0 + p.x + bf2f(rt.x) + bi.x;
    float v1 = a1 + p.y + bf2f(rt.y) + bi.y;
    float v2 = a2 + p.z + bf2f(rt.z) + bi.z;
    float v3 = a3 + p.w + bf2f(rt.w) + bi.w;

    // LN over 128 ch spread across 32-lane group (4 ch/lane)
    float s = v0 + v1 + v2 + v3;
    float s2 = v0 * v0 + v1 * v1 + v2 * v2 + v3 * v3;
#pragma unroll
    for (int m = 16; m >= 1; m >>= 1) {
        s += __shfl_xor(s, m);
        s2 += __shfl_xor(s2, m);
    }
    float mu = s * (1.0f / 128.0f);
    float rstd = rsqrtf(s2 * (1.0f / 128.0f) - mu * mu + 1e-5f);
    float4 ga = *(const float4*)&gamma[cb];
    float4 be = *(const float4*)&beta[cb];
    float y0 = (v0 - mu) * rstd * ga.x + be.x;
    float y1 = (v1 - mu) * rstd * ga.y + be.y;
    float y2 = (v2 - mu) * rstd * ga.z + be.z;
    float y3 = (v3 - mu) * rstd * ga.w + be.w;

    if (LAYER == 0) {
        y0 = y0 > 0.f ? y0 : 0.2f * y0;
        y1 = y1 > 0.f ? y1 : 0.2f * y1;
        y2 = y2 > 0.f ? y2 : 0.2f * y2;
        y3 = y3 > 0.f ? y3 : 0.2f * y3;
        if (lane < 32) {
            ushort4 o;
            o.x = f2bf(y0); o.y = f2bf(y1); o.z = f2bf(y2); o.w = f2bf(y3);
            *(ushort4*)&((ushortT*)outp)[(size_t)n * 128 + cb] = o;
        }
    } else {
        float t = y0 + y1 + y2 + y3;
        float t2 = y0 * y0 + y1 * y1 + y2 * y2 + y3 * y3;
#pragma unroll
        for (int m = 16; m >= 1; m >>= 1) {
            t += __shfl_xor(t, m);
            t2 += __shfl_xor(t2, m);
        }
        float mu2 = t * (1.0f / 128.0f);
        float rstd2 = rsqrtf(t2 * (1.0f / 128.0f) - mu2 * mu2 + 1e-5f);
        float4 go = *(const float4*)&gout[cb];
        float4 bo = *(const float4*)&bout[cb];
        if (lane < 32) {
            float4 o;
            o.x = (y0 - mu2) * rstd2 * go.x + bo.x;
            o.y = (y1 - mu2) * rstd2 * go.y + bo.y;
            o.z = (y2 - mu2) * rstd2 * go.z + bo.z;
            o.w = (y3 - mu2) * rstd2 * go.w + bo.w;
            *(float4*)&((float*)outp)[(size_t)n * 128 + cb] = o;
        }
    }
}

// ---------------------------------------------------------------------------
extern "C" void kernel_launch(void* const* d_in, const int* in_sizes, int n_in,
                              void* d_out, int out_size, void* d_ws, size_t ws_size,
                              hipStream_t stream) {
    const float* x     = (const float*)d_in[0];
    const int*   eidx  = (const int*)d_in[1];
    const int*   etyp  = (const int*)d_in[2];
    const float* W0    = (const float*)d_in[3];
    const float* root0 = (const float*)d_in[4];
    const float* b0    = (const float*)d_in[5];
    const float* g0    = (const float*)d_in[6];
    const float* be0   = (const float*)d_in[7];
    const float* W1    = (const float*)d_in[8];
    const float* root1 = (const float*)d_in[9];
    const float* b1    = (const float*)d_in[10];
    const float* g1    = (const float*)d_in[11];
    const float* be1   = (const float*)d_in[12];
    const float* gout  = (const float*)d_in[13];
    const float* bout  = (const float*)d_in[14];

    const int* esrc = eidx;
    const int* edst = eidx + EE;

    // workspace: trans | h1 | Bpack | UNION{ xb (layer0 GEMM only) , CSR }
    const size_t sz_trans = (size_t)NN * 512 * 2;   // 102.4 MB
    const size_t sz_h1    = (size_t)NN * 128 * 2;   //  25.6 MB
    const size_t sz_bpack = (size_t)512 * 256 * 2;  //   0.25 MB
    const size_t sz_xb    = (size_t)NN * 256 * 2;   //  51.2 MB
    const size_t sz_cnt3  = (size_t)NN * 3 * 4;
    const size_t sz_rp    = (size_t)(NN + 1) * 4;
    const size_t sz_cur   = (size_t)NN * 4;
    const size_t sz_elist = (size_t)EE * 4;
    const size_t sz_csr   = sz_cnt3 + sz_rp + sz_cur + sz_elist;  // ~8.4 MB
    const size_t sz_union = sz_xb > sz_csr ? sz_xb : sz_csr;
    if (ws_size < sz_trans + sz_h1 + sz_bpack + sz_union) return;

    char* ws = (char*)d_ws;
    ushortT* trans = (ushortT*)ws; ws += sz_trans;
    ushortT* h1    = (ushortT*)ws; ws += sz_h1;
    ushortT* Bpack = (ushortT*)ws; ws += sz_bpack;
    char* uni = ws;
    ushortT* xb    = (ushortT*)uni;                       // alive: cvt..gemm0
    int*     cnt3  = (int*)uni;                           // alive: after gemm0
    int*     rowp  = (int*)(uni + sz_cnt3);
    int*     cursor= (int*)(uni + sz_cnt3 + sz_rp);
    uintT*   elist = (uintT*)(uni + sz_cnt3 + sz_rp + sz_cur);

    dim3 ggrid((NN + 127) / 128, 4);

    // ---- layer 0 GEMM (K=256) on pre-converted bf16 x ----
    cvt_kernel<<<2048, 256, 0, stream>>>(x, xb);
    bpack_kernel<256><<<(512 * 256 + 255) / 256, 256, 0, stream>>>(W0, root0, Bpack);
    gemm_mfma_kernel<256><<<ggrid, 256, 0, stream>>>(xb, Bpack, trans, NN);

    // ---- CSR build (xb now dead; reuse region) ----
    hipMemsetAsync(cnt3, 0, sz_cnt3, stream);
    hipMemsetAsync(cursor, 0, sz_cur, stream);
    count3_kernel<<<(EE + 255) / 256, 256, 0, stream>>>(edst, etyp, cnt3);
    scan_kernel<<<1, 1024, 0, stream>>>(cnt3, rowp);
    fill_kernel<<<(EE + 255) / 256, 256, 0, stream>>>(esrc, edst, etyp, rowp, cursor, elist);

    // ---- layer 0 aggregate + finalize ----
    agg_finalize_kernel<0><<<NN / 2, 256, 0, stream>>>(trans, elist, rowp, cnt3, b0, g0, be0,
                                                       nullptr, nullptr, h1);

    // ---- layer 1 (K=128) ----
    bpack_kernel<128><<<(512 * 128 + 255) / 256, 256, 0, stream>>>(W1, root1, Bpack);
    gemm_mfma_kernel<128><<<ggrid, 256, 0, stream>>>(h1, Bpack, trans, NN);
    agg_finalize_kernel<1><<<NN / 2, 256, 0, stream>>>(trans, elist, rowp, cnt3, b1, g1, be1,
                                                       gout, bout, d_out);
}

// Round 5
// 464.791 us; speedup vs baseline: 1.4337x; 1.4337x over previous
//
#include <hip/hip_runtime.h>

#define NN 100000
#define EE 1600000

typedef unsigned short ushortT;
typedef unsigned int uintT;
typedef __attribute__((ext_vector_type(4))) float f32x4;
typedef __attribute__((ext_vector_type(8))) short bf16x8;

__device__ inline float bf2f(ushortT b) {
    return __uint_as_float(((uintT)b) << 16);
}
__device__ inline ushortT f2bf(float f) {
    uintT u = __float_as_uint(f);
    u += 0x7FFFu + ((u >> 16) & 1u);  // RNE
    return (ushortT)(u >> 16);
}

__device__ inline void gload_lds16(const void* g, void* l) {
    __builtin_amdgcn_global_load_lds((const __attribute__((address_space(1))) void*)g,
                                     (__attribute__((address_space(3))) void*)l, 16, 0, 0);
}

// ---------------------------------------------------------------------------
// f32 -> bf16 bulk convert (x -> xb)
// ---------------------------------------------------------------------------
__global__ __launch_bounds__(256) void cvt_kernel(const float* __restrict__ x,
                                                  ushortT* __restrict__ xb) {
    const int total = NN * 256 / 4;
    for (int i = blockIdx.x * 256 + threadIdx.x; i < total; i += gridDim.x * 256) {
        float4 v = ((const float4*)x)[i];
        ushort4 o;
        o.x = f2bf(v.x); o.y = f2bf(v.y); o.z = f2bf(v.z); o.w = f2bf(v.w);
        ((ushort4*)xb)[i] = o;
    }
}

// ---------------------------------------------------------------------------
// histogram of edges per (dst, rel)
// ---------------------------------------------------------------------------
__global__ __launch_bounds__(256) void count3_kernel(const int* __restrict__ edst,
                                                     const int* __restrict__ etyp,
                                                     int* __restrict__ cnt3) {
    int e = blockIdx.x * blockDim.x + threadIdx.x;
    if (e >= EE) return;
    int d = edst[e], r = etyp[e];
    if ((unsigned)d >= NN || (unsigned)r >= 3u) return;
    atomicAdd(&cnt3[d * 3 + r], 1);
}

// ---------------------------------------------------------------------------
// hierarchical exclusive scan of node degrees
// ---------------------------------------------------------------------------
__global__ __launch_bounds__(1024) void scan1_kernel(const int* __restrict__ cnt3,
                                                     int* __restrict__ row_ptr,
                                                     int* __restrict__ bsum) {
    __shared__ int wpart[16];
    const int tid = threadIdx.x;
    const int lane = tid & 63, wid = tid >> 6;
    const int n = blockIdx.x * 1024 + tid;
    int d = 0;
    if (n < NN) d = cnt3[n * 3] + cnt3[n * 3 + 1] + cnt3[n * 3 + 2];
    int v = d;
#pragma unroll
    for (int off = 1; off < 64; off <<= 1) {
        int t = __shfl_up(v, off);
        if (lane >= off) v += t;
    }
    if (lane == 63) wpart[wid] = v;
    __syncthreads();
    if (wid == 0) {
        int p = (lane < 16) ? wpart[lane] : 0;
#pragma unroll
        for (int off = 1; off < 16; off <<= 1) {
            int t = __shfl_up(p, off);
            if (lane >= off) p += t;
        }
        if (lane < 16) wpart[lane] = p;
    }
    __syncthreads();
    int excl = (wid ? wpart[wid - 1] : 0) + v - d;
    if (n < NN) row_ptr[n] = excl;
    if (tid == 1023) bsum[blockIdx.x] = wpart[15];
}

__global__ __launch_bounds__(128) void scan2_kernel(int* __restrict__ bsum,
                                                    int* __restrict__ row_ptr) {
    __shared__ int wp[2];
    const int t = threadIdx.x;  // 0..127, covers 98 blocks
    const int lane = t & 63, w = t >> 6;
    int v = (t < 98) ? bsum[t] : 0;
    int inc = v;
#pragma unroll
    for (int off = 1; off < 64; off <<= 1) {
        int u = __shfl_up(inc, off);
        if (lane >= off) inc += u;
    }
    if (lane == 63) wp[w] = inc;
    __syncthreads();
    int excl = inc - v + (w ? wp[0] : 0);
    if (t < 98) bsum[t] = excl;
    if (t == 127) row_ptr[NN] = wp[0] + wp[1];
}

__global__ __launch_bounds__(256) void scan3_kernel(int* __restrict__ row_ptr,
                                                    const int* __restrict__ bsum) {
    int n = blockIdx.x * 256 + threadIdx.x;
    if (n < NN) row_ptr[n] += bsum[n >> 10];
}

// ---------------------------------------------------------------------------
// fill CSR edge list
// ---------------------------------------------------------------------------
__global__ __launch_bounds__(256) void fill_kernel(const int* __restrict__ esrc,
                                                   const int* __restrict__ edst,
                                                   const int* __restrict__ etyp,
                                                   const int* __restrict__ row_ptr,
                                                   int* __restrict__ cursor,
                                                   uintT* __restrict__ elist) {
    int e = blockIdx.x * blockDim.x + threadIdx.x;
    if (e >= EE) return;
    int s = esrc[e], d = edst[e], r = etyp[e];
    if ((unsigned)s >= NN || (unsigned)d >= NN || (unsigned)r >= 3u) return;
    int pos = row_ptr[d] + atomicAdd(&cursor[d], 1);
    elist[pos] = ((uintT)s << 2) | (uintT)r;
}

// ---------------------------------------------------------------------------
// pack [W|root] into MFMA-fragment-ready bf16 layout
// ---------------------------------------------------------------------------
template <int K>
__global__ __launch_bounds__(256) void bpack_kernel(const float* __restrict__ W,
                                                    const float* __restrict__ root,
                                                    ushortT* __restrict__ Bpack) {
    constexpr int KB = K / 32;
    int idx = blockIdx.x * blockDim.x + threadIdx.x;
    if (idx >= 512 * K) return;
    int j = idx & 7;
    int l = (idx >> 3) & 63;
    int blk = idx >> 9;  // nblk*KB + kblk
    int kb = blk % KB, nblk = blk / KB;
    int k = kb * 32 + (l >> 4) * 8 + j;
    int m = nblk * 16 + (l & 15);
    float v;
    if (m < 384) {
        v = W[(((size_t)(m >> 7)) * K + k) * 128 + (m & 127)];
    } else {
        v = root[(size_t)k * 128 + (m - 384)];
    }
    Bpack[idx] = f2bf(v);
}

// ---------------------------------------------------------------------------
// bf16 MFMA GEMM: C[N,512](bf16) = A[N,K](bf16) @ B[K,512]
// 128x128 tile, 4 waves (2x2), BK=32, A via global_load_lds (pre-swizzled src,
// linear LDS dest, double-buffered), B fragment-packed from global (L2).
// ---------------------------------------------------------------------------
__device__ inline int swz_off(int r, int g) {  // ushort offset of 16B unit
    return r * 32 + ((g ^ ((r >> 1) & 3)) << 3);
}

template <int K>
__global__ __launch_bounds__(256) void gemm_mfma_kernel(const ushortT* __restrict__ A,
                                                        const ushortT* __restrict__ Bpack,
                                                        ushortT* __restrict__ C, int N) {
    constexpr int KB = K / 32;
    __shared__ ushortT As[2][128 * 32];  // 2 x 8 KB

    const int tid = threadIdx.x;
    const int lane = tid & 63;
    const int wid = tid >> 6;
    const int wr = wid >> 1, wc = wid & 1;
    const int bm = blockIdx.x * 128;
    const int bnblk = blockIdx.y * 8;

    // staging: wave wid covers LDS granules U in [wid*128, (wid+1)*128), 2 instr
    // granule U: row r=U>>2, stored col g'=U&3 -> global col g = g' ^ ((r>>1)&3)
    size_t src_off[2];
#pragma unroll
    for (int t = 0; t < 2; ++t) {
        int U = (wid * 2 + t) * 64 + lane;
        int r = U >> 2;
        int g = (U & 3) ^ ((r >> 1) & 3);
        int row = bm + r;
        if (row > N - 1) row = N - 1;  // clamp: garbage rows never stored
        src_off[t] = (size_t)row * K + g * 8;
    }

    auto stage_issue = [&](int kblk, int buf) {
#pragma unroll
        for (int t = 0; t < 2; ++t)
            gload_lds16(&A[src_off[t] + kblk * 32], &As[buf][(wid * 2 + t) * 512]);
    };
    f32x4 acc[4][4] = {};
    bf16x8 breg[4], bnext[4];
    auto load_b = [&](int kblk, bf16x8* out) {
#pragma unroll
        for (int nb = 0; nb < 4; ++nb) {
            int nblk = bnblk + wc * 4 + nb;
            out[nb] = *(const bf16x8*)&Bpack[((size_t)(nblk * KB + kblk) * 64 + lane) * 8];
        }
    };

    stage_issue(0, 0);
    load_b(0, breg);

    for (int kblk = 0; kblk < KB; ++kblk) {
        const int cur = kblk & 1;
        __syncthreads();  // compiler drains vmcnt -> As[cur] + breg ready
        if (kblk + 1 < KB) stage_issue(kblk + 1, cur ^ 1);
        bf16x8 afrag[4];
#pragma unroll
        for (int mb = 0; mb < 4; ++mb) {
            int fr = wr * 64 + mb * 16 + (lane & 15);
            afrag[mb] = *(const bf16x8*)&As[cur][swz_off(fr, lane >> 4)];
        }
        if (kblk + 1 < KB) load_b(kblk + 1, bnext);
#pragma unroll
        for (int mb = 0; mb < 4; ++mb)
#pragma unroll
            for (int nb = 0; nb < 4; ++nb)
                acc[mb][nb] = __builtin_amdgcn_mfma_f32_16x16x32_bf16(
                    afrag[mb], breg[nb], acc[mb][nb], 0, 0, 0);
        if (kblk + 1 < KB) {
#pragma unroll
            for (int nb = 0; nb < 4; ++nb) breg[nb] = bnext[nb];
        }
    }

    // C/D layout: col=lane&15, row=(lane>>4)*4+q  [guide m89/m91]
#pragma unroll
    for (int mb = 0; mb < 4; ++mb) {
        int row0 = bm + wr * 64 + mb * 16 + ((lane >> 4) << 2);
#pragma unroll
        for (int nb = 0; nb < 4; ++nb) {
            int col = (bnblk + wc * 4 + nb) * 16 + (lane & 15);
#pragma unroll
            for (int q = 0; q < 4; ++q) {
                int row = row0 + q;
                if (row < N) C[(size_t)row * 512 + col] = f2bf(acc[mb][nb][q]);
            }
        }
    }
}

// ---------------------------------------------------------------------------
// fused CSR aggregation + root + bias + LN (+leaky / +LN2): one wave per node,
// 4 edges in flight, two independent accumulator pairs. Grid NN/4, 256 thr.
// ---------------------------------------------------------------------------
template <int LAYER>
__global__ __launch_bounds__(256) void agg_finalize_kernel(
    const ushortT* __restrict__ trans, const uintT* __restrict__ elist,
    const int* __restrict__ row_ptr, const int* __restrict__ cnt3,
    const float* __restrict__ bias, const float* __restrict__ gamma,
    const float* __restrict__ beta, const float* __restrict__ gout,
    const float* __restrict__ bout, void* __restrict__ outp) {
    const int wid = threadIdx.x >> 6;
    const int lane = threadIdx.x & 63;
    const int n = blockIdx.x * 4 + wid;  // grid exact: 25000*4 = NN
    const int c2 = lane * 2;

    const int start = row_ptr[n];
    const int end = row_ptr[n + 1];
    const float i0 = 1.0f / fmaxf((float)cnt3[n * 3 + 0], 1.0f);
    const float i1 = 1.0f / fmaxf((float)cnt3[n * 3 + 1], 1.0f);
    const float i2 = 1.0f / fmaxf((float)cnt3[n * 3 + 2], 1.0f);

    float a0 = 0.f, a1 = 0.f, b0v = 0.f, b1v = 0.f;
    int i = start;
    for (; i + 3 < end; i += 4) {
        uintT e0 = elist[i], e1 = elist[i + 1], e2 = elist[i + 2], e3 = elist[i + 3];
        int s0 = e0 >> 2, r0 = e0 & 3;
        int s1 = e1 >> 2, r1 = e1 & 3;
        int s2 = e2 >> 2, r2 = e2 & 3;
        int s3 = e3 >> 2, r3 = e3 & 3;
        ushort2 u0 = *(const ushort2*)&trans[(size_t)s0 * 512 + r0 * 128 + c2];
        ushort2 u1 = *(const ushort2*)&trans[(size_t)s1 * 512 + r1 * 128 + c2];
        ushort2 u2 = *(const ushort2*)&trans[(size_t)s2 * 512 + r2 * 128 + c2];
        ushort2 u3 = *(const ushort2*)&trans[(size_t)s3 * 512 + r3 * 128 + c2];
        float w0 = r0 == 0 ? i0 : (r0 == 1 ? i1 : i2);
        float w1 = r1 == 0 ? i0 : (r1 == 1 ? i1 : i2);
        float w2 = r2 == 0 ? i0 : (r2 == 1 ? i1 : i2);
        float w3 = r3 == 0 ? i0 : (r3 == 1 ? i1 : i2);
        a0 += w0 * bf2f(u0.x) + w2 * bf2f(u2.x);
        a1 += w0 * bf2f(u0.y) + w2 * bf2f(u2.y);
        b0v += w1 * bf2f(u1.x) + w3 * bf2f(u3.x);
        b1v += w1 * bf2f(u1.y) + w3 * bf2f(u3.y);
    }
    for (; i < end; ++i) {
        uintT ev = elist[i];
        int s = ev >> 2, r = ev & 3;
        ushort2 u = *(const ushort2*)&trans[(size_t)s * 512 + r * 128 + c2];
        float w = r == 0 ? i0 : (r == 1 ? i1 : i2);
        a0 += w * bf2f(u.x);
        a1 += w * bf2f(u.y);
    }
    a0 += b0v;
    a1 += b1v;

    // + root + bias
    ushort2 rt = *(const ushort2*)&trans[(size_t)n * 512 + 384 + c2];
    float v0 = a0 + bf2f(rt.x) + bias[c2 + 0];
    float v1 = a1 + bf2f(rt.y) + bias[c2 + 1];

    // LN over 128 (each lane holds 2 channels)
    float s = v0 + v1, s2 = v0 * v0 + v1 * v1;
#pragma unroll
    for (int m = 32; m >= 1; m >>= 1) {
        s += __shfl_xor(s, m);
        s2 += __shfl_xor(s2, m);
    }
    float mu = s * (1.0f / 128.0f);
    float rstd = rsqrtf(s2 * (1.0f / 128.0f) - mu * mu + 1e-5f);
    float y0 = (v0 - mu) * rstd * gamma[c2 + 0] + beta[c2 + 0];
    float y1 = (v1 - mu) * rstd * gamma[c2 + 1] + beta[c2 + 1];

    if (LAYER == 0) {
        y0 = y0 > 0.f ? y0 : 0.2f * y0;
        y1 = y1 > 0.f ? y1 : 0.2f * y1;
        ushort2 o;
        o.x = f2bf(y0);
        o.y = f2bf(y1);
        *(ushort2*)&((ushortT*)outp)[(size_t)n * 128 + c2] = o;
    } else {
        float t = y0 + y1, t2 = y0 * y0 + y1 * y1;
#pragma unroll
        for (int m = 32; m >= 1; m >>= 1) {
            t += __shfl_xor(t, m);
            t2 += __shfl_xor(t2, m);
        }
        float mu2 = t * (1.0f / 128.0f);
        float rstd2 = rsqrtf(t2 * (1.0f / 128.0f) - mu2 * mu2 + 1e-5f);
        float2 o;
        o.x = (y0 - mu2) * rstd2 * gout[c2 + 0] + bout[c2 + 0];
        o.y = (y1 - mu2) * rstd2 * gout[c2 + 1] + bout[c2 + 1];
        *(float2*)&((float*)outp)[(size_t)n * 128 + c2] = o;
    }
}

// ---------------------------------------------------------------------------
extern "C" void kernel_launch(void* const* d_in, const int* in_sizes, int n_in,
                              void* d_out, int out_size, void* d_ws, size_t ws_size,
                              hipStream_t stream) {
    const float* x     = (const float*)d_in[0];
    const int*   eidx  = (const int*)d_in[1];
    const int*   etyp  = (const int*)d_in[2];
    const float* W0    = (const float*)d_in[3];
    const float* root0 = (const float*)d_in[4];
    const float* b0    = (const float*)d_in[5];
    const float* g0    = (const float*)d_in[6];
    const float* be0   = (const float*)d_in[7];
    const float* W1    = (const float*)d_in[8];
    const float* root1 = (const float*)d_in[9];
    const float* b1    = (const float*)d_in[10];
    const float* g1    = (const float*)d_in[11];
    const float* be1   = (const float*)d_in[12];
    const float* gout  = (const float*)d_in[13];
    const float* bout  = (const float*)d_in[14];

    const int* esrc = eidx;
    const int* edst = eidx + EE;

    // workspace: trans | h1 | Bpack | UNION{ xb (layer0 GEMM), CSR }
    const size_t sz_trans = (size_t)NN * 512 * 2;   // 102.4 MB
    const size_t sz_h1    = (size_t)NN * 128 * 2;   //  25.6 MB
    const size_t sz_bpack = (size_t)512 * 256 * 2;  //   0.25 MB
    const size_t sz_xb    = (size_t)NN * 256 * 2;   //  51.2 MB
    const size_t sz_cnt3  = (size_t)NN * 3 * 4;
    const size_t sz_rp    = (size_t)(NN + 1) * 4;
    const size_t sz_cur   = (size_t)NN * 4;
    const size_t sz_bsum  = (size_t)128 * 4;
    const size_t sz_elist = (size_t)EE * 4;
    const size_t sz_csr   = sz_cnt3 + sz_rp + sz_cur + sz_bsum + sz_elist;
    const size_t sz_union = sz_xb > sz_csr ? sz_xb : sz_csr;
    if (ws_size < sz_trans + sz_h1 + sz_bpack + sz_union) return;

    char* ws = (char*)d_ws;
    ushortT* trans = (ushortT*)ws; ws += sz_trans;
    ushortT* h1    = (ushortT*)ws; ws += sz_h1;
    ushortT* Bpack = (ushortT*)ws; ws += sz_bpack;
    char* uni = ws;
    ushortT* xb    = (ushortT*)uni;  // alive: cvt..gemm0
    int*     cnt3  = (int*)uni;      // alive: after gemm0
    int*     rowp  = (int*)(uni + sz_cnt3);
    int*     cursor= (int*)(uni + sz_cnt3 + sz_rp);
    int*     bsum  = (int*)(uni + sz_cnt3 + sz_rp + sz_cur);
    uintT*   elist = (uintT*)(uni + sz_cnt3 + sz_rp + sz_cur + sz_bsum);

    dim3 ggrid((NN + 127) / 128, 4);

    // ---- layer 0 GEMM (K=256) on pre-converted bf16 x ----
    cvt_kernel<<<2048, 256, 0, stream>>>(x, xb);
    bpack_kernel<256><<<(512 * 256 + 255) / 256, 256, 0, stream>>>(W0, root0, Bpack);
    gemm_mfma_kernel<256><<<ggrid, 256, 0, stream>>>(xb, Bpack, trans, NN);

    // ---- CSR build (xb now dead; reuse region) ----
    hipMemsetAsync(cnt3, 0, sz_cnt3 + sz_rp + sz_cur, stream);
    count3_kernel<<<(EE + 255) / 256, 256, 0, stream>>>(edst, etyp, cnt3);
    scan1_kernel<<<(NN + 1023) / 1024, 1024, 0, stream>>>(cnt3, rowp, bsum);
    scan2_kernel<<<1, 128, 0, stream>>>(bsum, rowp);
    scan3_kernel<<<(NN + 255) / 256, 256, 0, stream>>>(rowp, bsum);
    fill_kernel<<<(EE + 255) / 256, 256, 0, stream>>>(esrc, edst, etyp, rowp, cursor, elist);

    // ---- layer 0 aggregate + finalize ----
    agg_finalize_kernel<0><<<NN / 4, 256, 0, stream>>>(trans, elist, rowp, cnt3, b0, g0, be0,
                                                       nullptr, nullptr, h1);

    // ---- layer 1 (K=128) ----
    bpack_kernel<128><<<(512 * 128 + 255) / 256, 256, 0, stream>>>(W1, root1, Bpack);
    gemm_mfma_kernel<128><<<ggrid, 256, 0, stream>>>(h1, Bpack, trans, NN);
    agg_finalize_kernel<1><<<NN / 4, 256, 0, stream>>>(trans, elist, rowp, cnt3, b1, g1, be1,
                                                       gout, bout, d_out);
}

// Round 6
// 437.014 us; speedup vs baseline: 1.5248x; 1.0636x over previous
//
#include <hip/hip_runtime.h>

#define NN 100000
#define EE 1600000

typedef unsigned short ushortT;
typedef unsigned int uintT;
typedef __attribute__((ext_vector_type(4))) float f32x4;
typedef __attribute__((ext_vector_type(8))) short bf16x8;

__device__ inline float bf2f(ushortT b) {
    return __uint_as_float(((uintT)b) << 16);
}
__device__ inline ushortT f2bf(float f) {
    uintT u = __float_as_uint(f);
    u += 0x7FFFu + ((u >> 16) & 1u);  // RNE
    return (ushortT)(u >> 16);
}

__device__ inline void gload_lds16(const void* g, void* l) {
    __builtin_amdgcn_global_load_lds((const __attribute__((address_space(1))) void*)g,
                                     (__attribute__((address_space(3))) void*)l, 16, 0, 0);
}

// ---------------------------------------------------------------------------
// f32 -> bf16 bulk convert (x -> xb)
// ---------------------------------------------------------------------------
__global__ __launch_bounds__(256) void cvt_kernel(const float* __restrict__ x,
                                                  ushortT* __restrict__ xb) {
    const int total = NN * 256 / 4;
    for (int i = blockIdx.x * 256 + threadIdx.x; i < total; i += gridDim.x * 256) {
        float4 v = ((const float4*)x)[i];
        ushort4 o;
        o.x = f2bf(v.x); o.y = f2bf(v.y); o.z = f2bf(v.z); o.w = f2bf(v.w);
        ((ushort4*)xb)[i] = o;
    }
}

// ---------------------------------------------------------------------------
// histogram of edges per (dst, rel), 4 edges/thread ILP
// ---------------------------------------------------------------------------
__global__ __launch_bounds__(256) void count3_kernel(const int* __restrict__ edst,
                                                     const int* __restrict__ etyp,
                                                     int* __restrict__ cnt3) {
    int base = blockIdx.x * 1024 + threadIdx.x;
#pragma unroll
    for (int t = 0; t < 4; ++t) {
        int e = base + t * 256;
        if (e < EE) {
            int d = edst[e], r = etyp[e];
            if ((unsigned)d < NN && (unsigned)r < 3u) atomicAdd(&cnt3[d * 3 + r], 1);
        }
    }
}

// ---------------------------------------------------------------------------
// hierarchical exclusive scan of node degrees
// ---------------------------------------------------------------------------
__global__ __launch_bounds__(1024) void scan1_kernel(const int* __restrict__ cnt3,
                                                     int* __restrict__ row_ptr,
                                                     int* __restrict__ bsum) {
    __shared__ int wpart[16];
    const int tid = threadIdx.x;
    const int lane = tid & 63, wid = tid >> 6;
    const int n = blockIdx.x * 1024 + tid;
    int d = 0;
    if (n < NN) d = cnt3[n * 3] + cnt3[n * 3 + 1] + cnt3[n * 3 + 2];
    int v = d;
#pragma unroll
    for (int off = 1; off < 64; off <<= 1) {
        int t = __shfl_up(v, off);
        if (lane >= off) v += t;
    }
    if (lane == 63) wpart[wid] = v;
    __syncthreads();
    if (wid == 0) {
        int p = (lane < 16) ? wpart[lane] : 0;
#pragma unroll
        for (int off = 1; off < 16; off <<= 1) {
            int t = __shfl_up(p, off);
            if (lane >= off) p += t;
        }
        if (lane < 16) wpart[lane] = p;
    }
    __syncthreads();
    int excl = (wid ? wpart[wid - 1] : 0) + v - d;
    if (n < NN) row_ptr[n] = excl;
    if (tid == 1023) bsum[blockIdx.x] = wpart[15];
}

__global__ __launch_bounds__(128) void scan2_kernel(int* __restrict__ bsum,
                                                    int* __restrict__ row_ptr) {
    __shared__ int wp[2];
    const int t = threadIdx.x;  // 0..127, covers 98 blocks
    const int lane = t & 63, w = t >> 6;
    int v = (t < 98) ? bsum[t] : 0;
    int inc = v;
#pragma unroll
    for (int off = 1; off < 64; off <<= 1) {
        int u = __shfl_up(inc, off);
        if (lane >= off) inc += u;
    }
    if (lane == 63) wp[w] = inc;
    __syncthreads();
    int excl = inc - v + (w ? wp[0] : 0);
    if (t < 98) bsum[t] = excl;
    if (t == 127) row_ptr[NN] = wp[0] + wp[1];
}

// finalize row_ptr and seed cursor = row_ptr (so fill skips the rowp read)
__global__ __launch_bounds__(256) void scan3_kernel(int* __restrict__ row_ptr,
                                                    int* __restrict__ cursor,
                                                    const int* __restrict__ bsum) {
    int n = blockIdx.x * 256 + threadIdx.x;
    if (n < NN) {
        int v = row_ptr[n] + bsum[n >> 10];
        row_ptr[n] = v;
        cursor[n] = v;
    }
}

// ---------------------------------------------------------------------------
// fill CSR edge list, 4 edges/thread ILP, cursor pre-seeded with row_ptr
// ---------------------------------------------------------------------------
__global__ __launch_bounds__(256) void fill_kernel(const int* __restrict__ esrc,
                                                   const int* __restrict__ edst,
                                                   const int* __restrict__ etyp,
                                                   int* __restrict__ cursor,
                                                   uintT* __restrict__ elist) {
    int base = blockIdx.x * 1024 + threadIdx.x;
#pragma unroll
    for (int t = 0; t < 4; ++t) {
        int e = base + t * 256;
        if (e < EE) {
            int s = esrc[e], d = edst[e], r = etyp[e];
            if ((unsigned)s < NN && (unsigned)d < NN && (unsigned)r < 3u) {
                int pos = atomicAdd(&cursor[d], 1);
                elist[pos] = ((uintT)s << 2) | (uintT)r;
            }
        }
    }
}

// ---------------------------------------------------------------------------
// pack [W|root] into MFMA-fragment-ready bf16 layout
// ---------------------------------------------------------------------------
template <int K>
__global__ __launch_bounds__(256) void bpack_kernel(const float* __restrict__ W,
                                                    const float* __restrict__ root,
                                                    ushortT* __restrict__ Bpack) {
    constexpr int KB = K / 32;
    int idx = blockIdx.x * blockDim.x + threadIdx.x;
    if (idx >= 512 * K) return;
    int j = idx & 7;
    int l = (idx >> 3) & 63;
    int blk = idx >> 9;  // nblk*KB + kblk
    int kb = blk % KB, nblk = blk / KB;
    int k = kb * 32 + (l >> 4) * 8 + j;
    int m = nblk * 16 + (l & 15);
    float v;
    if (m < 384) {
        v = W[(((size_t)(m >> 7)) * K + k) * 128 + (m & 127)];
    } else {
        v = root[(size_t)k * 128 + (m - 384)];
    }
    Bpack[idx] = f2bf(v);
}

// ---------------------------------------------------------------------------
// bf16 MFMA GEMM: C[N,512](bf16) = A[N,K](bf16) @ B[K,512]
// 128x128 tile, 4 waves (2x2), BK=32, A via global_load_lds (pre-swizzled src,
// linear LDS dest, double-buffered), B fragment-packed from global (L2).
// ---------------------------------------------------------------------------
__device__ inline int swz_off(int r, int g) {  // ushort offset of 16B unit
    return r * 32 + ((g ^ ((r >> 1) & 3)) << 3);
}

template <int K>
__global__ __launch_bounds__(256) void gemm_mfma_kernel(const ushortT* __restrict__ A,
                                                        const ushortT* __restrict__ Bpack,
                                                        ushortT* __restrict__ C, int N) {
    constexpr int KB = K / 32;
    __shared__ ushortT As[2][128 * 32];  // 2 x 8 KB

    const int tid = threadIdx.x;
    const int lane = tid & 63;
    const int wid = tid >> 6;
    const int wr = wid >> 1, wc = wid & 1;
    const int bm = blockIdx.x * 128;
    const int bnblk = blockIdx.y * 8;

    size_t src_off[2];
#pragma unroll
    for (int t = 0; t < 2; ++t) {
        int U = (wid * 2 + t) * 64 + lane;
        int r = U >> 2;
        int g = (U & 3) ^ ((r >> 1) & 3);
        int row = bm + r;
        if (row > N - 1) row = N - 1;  // clamp: garbage rows never stored
        src_off[t] = (size_t)row * K + g * 8;
    }

    auto stage_issue = [&](int kblk, int buf) {
#pragma unroll
        for (int t = 0; t < 2; ++t)
            gload_lds16(&A[src_off[t] + kblk * 32], &As[buf][(wid * 2 + t) * 512]);
    };
    f32x4 acc[4][4] = {};
    bf16x8 breg[4], bnext[4];
    auto load_b = [&](int kblk, bf16x8* out) {
#pragma unroll
        for (int nb = 0; nb < 4; ++nb) {
            int nblk = bnblk + wc * 4 + nb;
            out[nb] = *(const bf16x8*)&Bpack[((size_t)(nblk * KB + kblk) * 64 + lane) * 8];
        }
    };

    stage_issue(0, 0);
    load_b(0, breg);

    for (int kblk = 0; kblk < KB; ++kblk) {
        const int cur = kblk & 1;
        __syncthreads();
        if (kblk + 1 < KB) stage_issue(kblk + 1, cur ^ 1);
        bf16x8 afrag[4];
#pragma unroll
        for (int mb = 0; mb < 4; ++mb) {
            int fr = wr * 64 + mb * 16 + (lane & 15);
            afrag[mb] = *(const bf16x8*)&As[cur][swz_off(fr, lane >> 4)];
        }
        if (kblk + 1 < KB) load_b(kblk + 1, bnext);
#pragma unroll
        for (int mb = 0; mb < 4; ++mb)
#pragma unroll
            for (int nb = 0; nb < 4; ++nb)
                acc[mb][nb] = __builtin_amdgcn_mfma_f32_16x16x32_bf16(
                    afrag[mb], breg[nb], acc[mb][nb], 0, 0, 0);
        if (kblk + 1 < KB) {
#pragma unroll
            for (int nb = 0; nb < 4; ++nb) breg[nb] = bnext[nb];
        }
    }

    // C/D layout: col=lane&15, row=(lane>>4)*4+q  [guide m89/m91]
#pragma unroll
    for (int mb = 0; mb < 4; ++mb) {
        int row0 = bm + wr * 64 + mb * 16 + ((lane >> 4) << 2);
#pragma unroll
        for (int nb = 0; nb < 4; ++nb) {
            int col = (bnblk + wc * 4 + nb) * 16 + (lane & 15);
#pragma unroll
            for (int q = 0; q < 4; ++q) {
                int row = row0 + q;
                if (row < N) C[(size_t)row * 512 + col] = f2bf(acc[mb][nb][q]);
            }
        }
    }
}

// ---------------------------------------------------------------------------
// fused CSR aggregation + root + bias + LN (+leaky / +LN2): one wave per node.
// Scalarized edge addressing: elist words broadcast to SGPR via readlane,
// row byte-offset computed in SALU; 8 edges in flight, 4 accumulator pairs.
// ---------------------------------------------------------------------------
template <int LAYER>
__global__ __launch_bounds__(256) void agg_finalize_kernel(
    const ushortT* __restrict__ trans, const uintT* __restrict__ elist,
    const int* __restrict__ row_ptr, const int* __restrict__ cnt3,
    const float* __restrict__ bias, const float* __restrict__ gamma,
    const float* __restrict__ beta, const float* __restrict__ gout,
    const float* __restrict__ bout, void* __restrict__ outp) {
    const int wid = threadIdx.x >> 6;
    const int lane = threadIdx.x & 63;
    const int n = blockIdx.x * 4 + wid;  // grid exact: 25000*4 = NN
    const int c2 = lane * 2;
    const int cbyte = c2 * 2;  // byte offset within a 256B relation row

    const int start = row_ptr[n];
    const int end = row_ptr[n + 1];
    const float i0 = 1.0f / fmaxf((float)cnt3[n * 3 + 0], 1.0f);
    const float i1 = 1.0f / fmaxf((float)cnt3[n * 3 + 1], 1.0f);
    const float i2 = 1.0f / fmaxf((float)cnt3[n * 3 + 2], 1.0f);
    const char* tb = (const char*)trans;

    float p0 = 0.f, p1 = 0.f, q0 = 0.f, q1 = 0.f;
    float r0a = 0.f, r1a = 0.f, s0a = 0.f, s1a = 0.f;

    int i = start;
    for (; i + 7 < end; i += 8) {
        uintT evv = elist[i + (lane & 7)];  // one coalesced load covers 8 edges
#pragma unroll
        for (int k = 0; k < 8; ++k) {
            uintT ev = (uintT)__builtin_amdgcn_readlane((int)evv, k);  // SGPR
            uintT off = (ev >> 2) * 1024u + (ev & 3u) * 256u;          // SALU
            ushort2 u = *(const ushort2*)(tb + off + cbyte);
            int r = (int)(ev & 3u);
            float w = r == 0 ? i0 : (r == 1 ? i1 : i2);
            float f0 = w * bf2f(u.x), f1 = w * bf2f(u.y);
            if ((k & 3) == 0) { p0 += f0; p1 += f1; }
            else if ((k & 3) == 1) { q0 += f0; q1 += f1; }
            else if ((k & 3) == 2) { r0a += f0; r1a += f1; }
            else { s0a += f0; s1a += f1; }
        }
    }
    if (i < end) {
        int m = end - i;  // 1..7, wave-uniform
        int idx = i + (lane & 7);
        uintT evv = (lane & 7) < m ? elist[idx] : 0u;
#pragma unroll
        for (int k = 0; k < 7; ++k) {
            if (k < m) {
                uintT ev = (uintT)__builtin_amdgcn_readlane((int)evv, k);
                uintT off = (ev >> 2) * 1024u + (ev & 3u) * 256u;
                ushort2 u = *(const ushort2*)(tb + off + cbyte);
                int r = (int)(ev & 3u);
                float w = r == 0 ? i0 : (r == 1 ? i1 : i2);
                p0 += w * bf2f(u.x);
                p1 += w * bf2f(u.y);
            }
        }
    }
    float a0 = (p0 + q0) + (r0a + s0a);
    float a1 = (p1 + q1) + (r1a + s1a);

    // + root + bias
    ushort2 rt = *(const ushort2*)&trans[(size_t)n * 512 + 384 + c2];
    float v0 = a0 + bf2f(rt.x) + bias[c2 + 0];
    float v1 = a1 + bf2f(rt.y) + bias[c2 + 1];

    // LN over 128 (each lane holds 2 channels)
    float s = v0 + v1, s2 = v0 * v0 + v1 * v1;
#pragma unroll
    for (int m = 32; m >= 1; m >>= 1) {
        s += __shfl_xor(s, m);
        s2 += __shfl_xor(s2, m);
    }
    float mu = s * (1.0f / 128.0f);
    float rstd = rsqrtf(s2 * (1.0f / 128.0f) - mu * mu + 1e-5f);
    float y0 = (v0 - mu) * rstd * gamma[c2 + 0] + beta[c2 + 0];
    float y1 = (v1 - mu) * rstd * gamma[c2 + 1] + beta[c2 + 1];

    if (LAYER == 0) {
        y0 = y0 > 0.f ? y0 : 0.2f * y0;
        y1 = y1 > 0.f ? y1 : 0.2f * y1;
        ushort2 o;
        o.x = f2bf(y0);
        o.y = f2bf(y1);
        *(ushort2*)&((ushortT*)outp)[(size_t)n * 128 + c2] = o;
    } else {
        float t = y0 + y1, t2 = y0 * y0 + y1 * y1;
#pragma unroll
        for (int m = 32; m >= 1; m >>= 1) {
            t += __shfl_xor(t, m);
            t2 += __shfl_xor(t2, m);
        }
        float mu2 = t * (1.0f / 128.0f);
        float rstd2 = rsqrtf(t2 * (1.0f / 128.0f) - mu2 * mu2 + 1e-5f);
        float2 o;
        o.x = (y0 - mu2) * rstd2 * gout[c2 + 0] + bout[c2 + 0];
        o.y = (y1 - mu2) * rstd2 * gout[c2 + 1] + bout[c2 + 1];
        *(float2*)&((float*)outp)[(size_t)n * 128 + c2] = o;
    }
}

// ---------------------------------------------------------------------------
extern "C" void kernel_launch(void* const* d_in, const int* in_sizes, int n_in,
                              void* d_out, int out_size, void* d_ws, size_t ws_size,
                              hipStream_t stream) {
    const float* x     = (const float*)d_in[0];
    const int*   eidx  = (const int*)d_in[1];
    const int*   etyp  = (const int*)d_in[2];
    const float* W0    = (const float*)d_in[3];
    const float* root0 = (const float*)d_in[4];
    const float* b0    = (const float*)d_in[5];
    const float* g0    = (const float*)d_in[6];
    const float* be0   = (const float*)d_in[7];
    const float* W1    = (const float*)d_in[8];
    const float* root1 = (const float*)d_in[9];
    const float* b1    = (const float*)d_in[10];
    const float* g1    = (const float*)d_in[11];
    const float* be1   = (const float*)d_in[12];
    const float* gout  = (const float*)d_in[13];
    const float* bout  = (const float*)d_in[14];

    const int* esrc = eidx;
    const int* edst = eidx + EE;

    // workspace: trans | h1 | Bpack | UNION{ xb (layer0 GEMM), CSR }
    const size_t sz_trans = (size_t)NN * 512 * 2;   // 102.4 MB
    const size_t sz_h1    = (size_t)NN * 128 * 2;   //  25.6 MB
    const size_t sz_bpack = (size_t)512 * 256 * 2;  //   0.25 MB
    const size_t sz_xb    = (size_t)NN * 256 * 2;   //  51.2 MB
    const size_t sz_cnt3  = (size_t)NN * 3 * 4;
    const size_t sz_rp    = (size_t)(NN + 1) * 4;
    const size_t sz_cur   = (size_t)NN * 4;
    const size_t sz_bsum  = (size_t)128 * 4;
    const size_t sz_elist = (size_t)EE * 4;
    const size_t sz_csr   = sz_cnt3 + sz_rp + sz_cur + sz_bsum + sz_elist;
    const size_t sz_union = sz_xb > sz_csr ? sz_xb : sz_csr;
    if (ws_size < sz_trans + sz_h1 + sz_bpack + sz_union) return;

    char* ws = (char*)d_ws;
    ushortT* trans = (ushortT*)ws; ws += sz_trans;
    ushortT* h1    = (ushortT*)ws; ws += sz_h1;
    ushortT* Bpack = (ushortT*)ws; ws += sz_bpack;
    char* uni = ws;
    ushortT* xb    = (ushortT*)uni;  // alive: cvt..gemm0
    int*     cnt3  = (int*)uni;      // alive: after gemm0
    int*     rowp  = (int*)(uni + sz_cnt3);
    int*     cursor= (int*)(uni + sz_cnt3 + sz_rp);
    int*     bsum  = (int*)(uni + sz_cnt3 + sz_rp + sz_cur);
    uintT*   elist = (uintT*)(uni + sz_cnt3 + sz_rp + sz_cur + sz_bsum);

    dim3 ggrid((NN + 127) / 128, 4);

    // ---- layer 0 GEMM (K=256) on pre-converted bf16 x ----
    cvt_kernel<<<2048, 256, 0, stream>>>(x, xb);
    bpack_kernel<256><<<(512 * 256 + 255) / 256, 256, 0, stream>>>(W0, root0, Bpack);
    gemm_mfma_kernel<256><<<ggrid, 256, 0, stream>>>(xb, Bpack, trans, NN);

    // ---- CSR build (xb now dead; reuse region) ----
    hipMemsetAsync(cnt3, 0, sz_cnt3, stream);
    count3_kernel<<<(EE + 1023) / 1024, 256, 0, stream>>>(edst, etyp, cnt3);
    scan1_kernel<<<(NN + 1023) / 1024, 1024, 0, stream>>>(cnt3, rowp, bsum);
    scan2_kernel<<<1, 128, 0, stream>>>(bsum, rowp);
    scan3_kernel<<<(NN + 255) / 256, 256, 0, stream>>>(rowp, cursor, bsum);
    fill_kernel<<<(EE + 1023) / 1024, 256, 0, stream>>>(esrc, edst, etyp, cursor, elist);

    // ---- layer 0 aggregate + finalize ----
    agg_finalize_kernel<0><<<NN / 4, 256, 0, stream>>>(trans, elist, rowp, cnt3, b0, g0, be0,
                                                       nullptr, nullptr, h1);

    // ---- layer 1 (K=128) ----
    bpack_kernel<128><<<(512 * 128 + 255) / 256, 256, 0, stream>>>(W1, root1, Bpack);
    gemm_mfma_kernel<128><<<ggrid, 256, 0, stream>>>(h1, Bpack, trans, NN);
    agg_finalize_kernel<1><<<NN / 4, 256, 0, stream>>>(trans, elist, rowp, cnt3, b1, g1, be1,
                                                       gout, bout, d_out);
}

// Round 7
// 429.993 us; speedup vs baseline: 1.5497x; 1.0163x over previous
//
#include <hip/hip_runtime.h>

#define NN 100000
#define EE 1600000

// fused-grid partition constants
#define FB   1563            // fill/count3 blocks: ceil(EE/1024)
#define GBX  782             // gemm x-blocks: ceil(NN/128)
#define GB0  (GBX * 4)       // gemm blocks (y in [0,4))
#define PB0  512             // bpack<256> blocks
#define PB1  256             // bpack<128> blocks
#define CVB  2048            // cvt blocks

typedef unsigned short ushortT;
typedef unsigned int uintT;
typedef __attribute__((ext_vector_type(4))) float f32x4;
typedef __attribute__((ext_vector_type(8))) short bf16x8;

__device__ inline float bf2f(ushortT b) {
    return __uint_as_float(((uintT)b) << 16);
}
__device__ inline ushortT f2bf(float f) {
    uintT u = __float_as_uint(f);
    u += 0x7FFFu + ((u >> 16) & 1u);  // RNE
    return (ushortT)(u >> 16);
}

__device__ inline void gload_lds16(const void* g, void* l) {
    __builtin_amdgcn_global_load_lds((const __attribute__((address_space(1))) void*)g,
                                     (__attribute__((address_space(3))) void*)l, 16, 0, 0);
}

// ---------------------------------------------------------------------------
// role: f32 -> bf16 bulk convert (x -> xb), grid-stride over CVB blocks
// ---------------------------------------------------------------------------
__device__ void cvt_role(int bid, const float* __restrict__ x, ushortT* __restrict__ xb) {
    const int total = NN * 256 / 4;
    for (int i = bid * 256 + threadIdx.x; i < total; i += CVB * 256) {
        float4 v = ((const float4*)x)[i];
        ushort4 o;
        o.x = f2bf(v.x); o.y = f2bf(v.y); o.z = f2bf(v.z); o.w = f2bf(v.w);
        ((ushort4*)xb)[i] = o;
    }
}

// ---------------------------------------------------------------------------
// role: histogram of edges per (dst, rel), 4 edges/thread
// ---------------------------------------------------------------------------
__device__ void count3_role(int bid, const int* __restrict__ edst,
                            const int* __restrict__ etyp, int* __restrict__ cnt3) {
    int base = bid * 1024 + threadIdx.x;
#pragma unroll
    for (int t = 0; t < 4; ++t) {
        int e = base + t * 256;
        if (e < EE) {
            int d = edst[e], r = etyp[e];
            if ((unsigned)d < NN && (unsigned)r < 3u) atomicAdd(&cnt3[d * 3 + r], 1);
        }
    }
}

// ---------------------------------------------------------------------------
// role: fill CSR edge list, cursor pre-seeded with row_ptr
// ---------------------------------------------------------------------------
__device__ void fill_role(int bid, const int* __restrict__ esrc,
                          const int* __restrict__ edst, const int* __restrict__ etyp,
                          int* __restrict__ cursor, uintT* __restrict__ elist) {
    int base = bid * 1024 + threadIdx.x;
#pragma unroll
    for (int t = 0; t < 4; ++t) {
        int e = base + t * 256;
        if (e < EE) {
            int s = esrc[e], d = edst[e], r = etyp[e];
            if ((unsigned)s < NN && (unsigned)d < NN && (unsigned)r < 3u) {
                int pos = atomicAdd(&cursor[d], 1);
                elist[pos] = ((uintT)s << 2) | (uintT)r;
            }
        }
    }
}

// ---------------------------------------------------------------------------
// role: pack [W|root] into MFMA-fragment-ready bf16 layout
// ---------------------------------------------------------------------------
template <int K>
__device__ void bpack_role(int bid, const float* __restrict__ W,
                           const float* __restrict__ root, ushortT* __restrict__ Bpack) {
    constexpr int KB = K / 32;
    int idx = bid * 256 + threadIdx.x;
    if (idx >= 512 * K) return;
    int j = idx & 7;
    int l = (idx >> 3) & 63;
    int blk = idx >> 9;  // nblk*KB + kblk
    int kb = blk % KB, nblk = blk / KB;
    int k = kb * 32 + (l >> 4) * 8 + j;
    int m = nblk * 16 + (l & 15);
    float v;
    if (m < 384) {
        v = W[(((size_t)(m >> 7)) * K + k) * 128 + (m & 127)];
    } else {
        v = root[(size_t)k * 128 + (m - 384)];
    }
    Bpack[idx] = f2bf(v);
}

// ---------------------------------------------------------------------------
// role: bf16 MFMA GEMM 128x128 tile, 4 waves, BK=32, double-buffered LDS
// ---------------------------------------------------------------------------
__device__ inline int swz_off(int r, int g) {  // ushort offset of 16B unit
    return r * 32 + ((g ^ ((r >> 1) & 3)) << 3);
}

template <int K>
__device__ void gemm_role(int bx, int by, const ushortT* __restrict__ A,
                          const ushortT* __restrict__ Bpack, ushortT* __restrict__ C,
                          int N, ushortT* As /* [2][4096] */) {
    constexpr int KB = K / 32;
    const int tid = threadIdx.x;
    const int lane = tid & 63;
    const int wid = tid >> 6;
    const int wr = wid >> 1, wc = wid & 1;
    const int bm = bx * 128;
    const int bnblk = by * 8;

    size_t src_off[2];
#pragma unroll
    for (int t = 0; t < 2; ++t) {
        int U = (wid * 2 + t) * 64 + lane;
        int r = U >> 2;
        int g = (U & 3) ^ ((r >> 1) & 3);
        int row = bm + r;
        if (row > N - 1) row = N - 1;  // clamp: garbage rows never stored
        src_off[t] = (size_t)row * K + g * 8;
    }

    auto stage_issue = [&](int kblk, int buf) {
#pragma unroll
        for (int t = 0; t < 2; ++t)
            gload_lds16(&A[src_off[t] + kblk * 32], &As[buf * 4096 + (wid * 2 + t) * 512]);
    };
    f32x4 acc[4][4] = {};
    bf16x8 breg[4], bnext[4];
    auto load_b = [&](int kblk, bf16x8* out) {
#pragma unroll
        for (int nb = 0; nb < 4; ++nb) {
            int nblk = bnblk + wc * 4 + nb;
            out[nb] = *(const bf16x8*)&Bpack[((size_t)(nblk * KB + kblk) * 64 + lane) * 8];
        }
    };

    stage_issue(0, 0);
    load_b(0, breg);

    for (int kblk = 0; kblk < KB; ++kblk) {
        const int cur = kblk & 1;
        __syncthreads();
        if (kblk + 1 < KB) stage_issue(kblk + 1, cur ^ 1);
        bf16x8 afrag[4];
#pragma unroll
        for (int mb = 0; mb < 4; ++mb) {
            int fr = wr * 64 + mb * 16 + (lane & 15);
            afrag[mb] = *(const bf16x8*)&As[cur * 4096 + swz_off(fr, lane >> 4)];
        }
        if (kblk + 1 < KB) load_b(kblk + 1, bnext);
#pragma unroll
        for (int mb = 0; mb < 4; ++mb)
#pragma unroll
            for (int nb = 0; nb < 4; ++nb)
                acc[mb][nb] = __builtin_amdgcn_mfma_f32_16x16x32_bf16(
                    afrag[mb], breg[nb], acc[mb][nb], 0, 0, 0);
        if (kblk + 1 < KB) {
#pragma unroll
            for (int nb = 0; nb < 4; ++nb) breg[nb] = bnext[nb];
        }
    }

    // C/D layout: col=lane&15, row=(lane>>4)*4+q  [guide m89/m91]
#pragma unroll
    for (int mb = 0; mb < 4; ++mb) {
        int row0 = bm + wr * 64 + mb * 16 + ((lane >> 4) << 2);
#pragma unroll
        for (int nb = 0; nb < 4; ++nb) {
            int col = (bnblk + wc * 4 + nb) * 16 + (lane & 15);
#pragma unroll
            for (int q = 0; q < 4; ++q) {
                int row = row0 + q;
                if (row < N) C[(size_t)row * 512 + col] = f2bf(acc[mb][nb][q]);
            }
        }
    }
}

// ---------------------------------------------------------------------------
// K1: count3 || cvt || bpack<256>
// ---------------------------------------------------------------------------
__global__ __launch_bounds__(256) void k1_kernel(const int* __restrict__ edst,
                                                 const int* __restrict__ etyp,
                                                 int* __restrict__ cnt3,
                                                 const float* __restrict__ x,
                                                 ushortT* __restrict__ xb,
                                                 const float* __restrict__ W0,
                                                 const float* __restrict__ root0,
                                                 ushortT* __restrict__ Bpack0) {
    int bid = blockIdx.x;
    if (bid < FB) { count3_role(bid, edst, etyp, cnt3); return; }
    bid -= FB;
    if (bid < CVB) { cvt_role(bid, x, xb); return; }
    bid -= CVB;
    bpack_role<256>(bid, W0, root0, Bpack0);
}

// ---------------------------------------------------------------------------
// K5: fill || gemm0 || bpack<128>
// ---------------------------------------------------------------------------
__global__ __launch_bounds__(256) void k5_kernel(
    const int* __restrict__ esrc, const int* __restrict__ edst,
    const int* __restrict__ etyp, int* __restrict__ cursor, uintT* __restrict__ elist,
    const ushortT* __restrict__ xb, const ushortT* __restrict__ Bpack0,
    ushortT* __restrict__ trans, const float* __restrict__ W1,
    const float* __restrict__ root1, ushortT* __restrict__ Bpack1) {
    __shared__ ushortT As[2 * 4096];
    int bid = blockIdx.x;
    if (bid < FB) { fill_role(bid, esrc, edst, etyp, cursor, elist); return; }
    bid -= FB;
    if (bid < GB0) {
        gemm_role<256>(bid % GBX, bid / GBX, xb, Bpack0, trans, NN, As);
        return;
    }
    bid -= GB0;
    bpack_role<128>(bid, W1, root1, Bpack1);
}

// ---------------------------------------------------------------------------
// standalone gemm (layer 1)
// ---------------------------------------------------------------------------
__global__ __launch_bounds__(256) void gemm1_kernel(const ushortT* __restrict__ A,
                                                    const ushortT* __restrict__ Bpack,
                                                    ushortT* __restrict__ C) {
    __shared__ ushortT As[2 * 4096];
    gemm_role<128>(blockIdx.x % GBX, blockIdx.x / GBX, A, Bpack, C, NN, As);
}

// ---------------------------------------------------------------------------
// hierarchical exclusive scan of node degrees
// ---------------------------------------------------------------------------
__global__ __launch_bounds__(1024) void scan1_kernel(const int* __restrict__ cnt3,
                                                     int* __restrict__ row_ptr,
                                                     int* __restrict__ bsum) {
    __shared__ int wpart[16];
    const int tid = threadIdx.x;
    const int lane = tid & 63, wid = tid >> 6;
    const int n = blockIdx.x * 1024 + tid;
    int d = 0;
    if (n < NN) d = cnt3[n * 3] + cnt3[n * 3 + 1] + cnt3[n * 3 + 2];
    int v = d;
#pragma unroll
    for (int off = 1; off < 64; off <<= 1) {
        int t = __shfl_up(v, off);
        if (lane >= off) v += t;
    }
    if (lane == 63) wpart[wid] = v;
    __syncthreads();
    if (wid == 0) {
        int p = (lane < 16) ? wpart[lane] : 0;
#pragma unroll
        for (int off = 1; off < 16; off <<= 1) {
            int t = __shfl_up(p, off);
            if (lane >= off) p += t;
        }
        if (lane < 16) wpart[lane] = p;
    }
    __syncthreads();
    int excl = (wid ? wpart[wid - 1] : 0) + v - d;
    if (n < NN) row_ptr[n] = excl;
    if (tid == 1023) bsum[blockIdx.x] = wpart[15];
}

__global__ __launch_bounds__(128) void scan2_kernel(int* __restrict__ bsum,
                                                    int* __restrict__ row_ptr) {
    __shared__ int wp[2];
    const int t = threadIdx.x;  // 0..127, covers 98 blocks
    const int lane = t & 63, w = t >> 6;
    int v = (t < 98) ? bsum[t] : 0;
    int inc = v;
#pragma unroll
    for (int off = 1; off < 64; off <<= 1) {
        int u = __shfl_up(inc, off);
        if (lane >= off) inc += u;
    }
    if (lane == 63) wp[w] = inc;
    __syncthreads();
    int excl = inc - v + (w ? wp[0] : 0);
    if (t < 98) bsum[t] = excl;
    if (t == 127) row_ptr[NN] = wp[0] + wp[1];
}

__global__ __launch_bounds__(256) void scan3_kernel(int* __restrict__ row_ptr,
                                                    int* __restrict__ cursor,
                                                    const int* __restrict__ bsum) {
    int n = blockIdx.x * 256 + threadIdx.x;
    if (n < NN) {
        int v = row_ptr[n] + bsum[n >> 10];
        row_ptr[n] = v;
        cursor[n] = v;
    }
}

// ---------------------------------------------------------------------------
// fused CSR aggregation + root + bias + LN (+leaky / +LN2): one wave per node.
// elist words broadcast to SGPR via readlane; SALU row offsets; 8 in flight.
// ---------------------------------------------------------------------------
template <int LAYER>
__global__ __launch_bounds__(256) void agg_finalize_kernel(
    const ushortT* __restrict__ trans, const uintT* __restrict__ elist,
    const int* __restrict__ row_ptr, const int* __restrict__ cnt3,
    const float* __restrict__ bias, const float* __restrict__ gamma,
    const float* __restrict__ beta, const float* __restrict__ gout,
    const float* __restrict__ bout, void* __restrict__ outp) {
    const int wid = threadIdx.x >> 6;
    const int lane = threadIdx.x & 63;
    const int n = blockIdx.x * 4 + wid;  // grid exact: 25000*4 = NN
    const int c2 = lane * 2;
    const int cbyte = c2 * 2;

    const int start = row_ptr[n];
    const int end = row_ptr[n + 1];
    const float i0 = 1.0f / fmaxf((float)cnt3[n * 3 + 0], 1.0f);
    const float i1 = 1.0f / fmaxf((float)cnt3[n * 3 + 1], 1.0f);
    const float i2 = 1.0f / fmaxf((float)cnt3[n * 3 + 2], 1.0f);
    const char* tb = (const char*)trans;

    float p0 = 0.f, p1 = 0.f, q0 = 0.f, q1 = 0.f;
    float r0a = 0.f, r1a = 0.f, s0a = 0.f, s1a = 0.f;

    int i = start;
    for (; i + 7 < end; i += 8) {
        uintT evv = elist[i + (lane & 7)];
#pragma unroll
        for (int k = 0; k < 8; ++k) {
            uintT ev = (uintT)__builtin_amdgcn_readlane((int)evv, k);
            uintT off = (ev >> 2) * 1024u + (ev & 3u) * 256u;
            ushort2 u = *(const ushort2*)(tb + off + cbyte);
            int r = (int)(ev & 3u);
            float w = r == 0 ? i0 : (r == 1 ? i1 : i2);
            float f0 = w * bf2f(u.x), f1 = w * bf2f(u.y);
            if ((k & 3) == 0) { p0 += f0; p1 += f1; }
            else if ((k & 3) == 1) { q0 += f0; q1 += f1; }
            else if ((k & 3) == 2) { r0a += f0; r1a += f1; }
            else { s0a += f0; s1a += f1; }
        }
    }
    if (i < end) {
        int m = end - i;  // 1..7, wave-uniform
        uintT evv = (lane & 7) < m ? elist[i + (lane & 7)] : 0u;
#pragma unroll
        for (int k = 0; k < 7; ++k) {
            if (k < m) {
                uintT ev = (uintT)__builtin_amdgcn_readlane((int)evv, k);
                uintT off = (ev >> 2) * 1024u + (ev & 3u) * 256u;
                ushort2 u = *(const ushort2*)(tb + off + cbyte);
                int r = (int)(ev & 3u);
                float w = r == 0 ? i0 : (r == 1 ? i1 : i2);
                p0 += w * bf2f(u.x);
                p1 += w * bf2f(u.y);
            }
        }
    }
    float a0 = (p0 + q0) + (r0a + s0a);
    float a1 = (p1 + q1) + (r1a + s1a);

    ushort2 rt = *(const ushort2*)&trans[(size_t)n * 512 + 384 + c2];
    float v0 = a0 + bf2f(rt.x) + bias[c2 + 0];
    float v1 = a1 + bf2f(rt.y) + bias[c2 + 1];

    float s = v0 + v1, s2 = v0 * v0 + v1 * v1;
#pragma unroll
    for (int m = 32; m >= 1; m >>= 1) {
        s += __shfl_xor(s, m);
        s2 += __shfl_xor(s2, m);
    }
    float mu = s * (1.0f / 128.0f);
    float rstd = rsqrtf(s2 * (1.0f / 128.0f) - mu * mu + 1e-5f);
    float y0 = (v0 - mu) * rstd * gamma[c2 + 0] + beta[c2 + 0];
    float y1 = (v1 - mu) * rstd * gamma[c2 + 1] + beta[c2 + 1];

    if (LAYER == 0) {
        y0 = y0 > 0.f ? y0 : 0.2f * y0;
        y1 = y1 > 0.f ? y1 : 0.2f * y1;
        ushort2 o;
        o.x = f2bf(y0);
        o.y = f2bf(y1);
        *(ushort2*)&((ushortT*)outp)[(size_t)n * 128 + c2] = o;
    } else {
        float t = y0 + y1, t2 = y0 * y0 + y1 * y1;
#pragma unroll
        for (int m = 32; m >= 1; m >>= 1) {
            t += __shfl_xor(t, m);
            t2 += __shfl_xor(t2, m);
        }
        float mu2 = t * (1.0f / 128.0f);
        float rstd2 = rsqrtf(t2 * (1.0f / 128.0f) - mu2 * mu2 + 1e-5f);
        float2 o;
        o.x = (y0 - mu2) * rstd2 * gout[c2 + 0] + bout[c2 + 0];
        o.y = (y1 - mu2) * rstd2 * gout[c2 + 1] + bout[c2 + 1];
        *(float2*)&((float*)outp)[(size_t)n * 128 + c2] = o;
    }
}

// ---------------------------------------------------------------------------
extern "C" void kernel_launch(void* const* d_in, const int* in_sizes, int n_in,
                              void* d_out, int out_size, void* d_ws, size_t ws_size,
                              hipStream_t stream) {
    const float* x     = (const float*)d_in[0];
    const int*   eidx  = (const int*)d_in[1];
    const int*   etyp  = (const int*)d_in[2];
    const float* W0    = (const float*)d_in[3];
    const float* root0 = (const float*)d_in[4];
    const float* b0    = (const float*)d_in[5];
    const float* g0    = (const float*)d_in[6];
    const float* be0   = (const float*)d_in[7];
    const float* W1    = (const float*)d_in[8];
    const float* root1 = (const float*)d_in[9];
    const float* b1    = (const float*)d_in[10];
    const float* g1    = (const float*)d_in[11];
    const float* be1   = (const float*)d_in[12];
    const float* gout  = (const float*)d_in[13];
    const float* bout  = (const float*)d_in[14];

    const int* esrc = eidx;
    const int* edst = eidx + EE;

    // workspace: trans | h1 | Bpack0 | Bpack1 | xb | CSR   (~196 MB)
    const size_t sz_trans  = (size_t)NN * 512 * 2;   // 102.4 MB
    const size_t sz_h1     = (size_t)NN * 128 * 2;   //  25.6 MB
    const size_t sz_bpack0 = (size_t)512 * 256 * 2;  //   0.25 MB
    const size_t sz_bpack1 = (size_t)512 * 128 * 2;  //   0.125 MB
    const size_t sz_xb     = (size_t)NN * 256 * 2;   //  51.2 MB
    const size_t sz_cnt3   = (size_t)NN * 3 * 4;
    const size_t sz_rp     = (size_t)(NN + 1) * 4;
    const size_t sz_cur    = (size_t)NN * 4;
    const size_t sz_bsum   = (size_t)128 * 4;
    const size_t sz_elist  = (size_t)EE * 4;
    const size_t sz_csr    = sz_cnt3 + sz_rp + sz_cur + sz_bsum + sz_elist;
    if (ws_size < sz_trans + sz_h1 + sz_bpack0 + sz_bpack1 + sz_xb + sz_csr) return;

    char* ws = (char*)d_ws;
    ushortT* trans  = (ushortT*)ws; ws += sz_trans;
    ushortT* h1     = (ushortT*)ws; ws += sz_h1;
    ushortT* Bpack0 = (ushortT*)ws; ws += sz_bpack0;
    ushortT* Bpack1 = (ushortT*)ws; ws += sz_bpack1;
    ushortT* xb     = (ushortT*)ws; ws += sz_xb;
    int*     cnt3   = (int*)ws;     ws += sz_cnt3;
    int*     rowp   = (int*)ws;     ws += sz_rp;
    int*     cursor = (int*)ws;     ws += sz_cur;
    int*     bsum   = (int*)ws;     ws += sz_bsum;
    uintT*   elist  = (uintT*)ws;   ws += sz_elist;

    hipMemsetAsync(cnt3, 0, sz_cnt3, stream);

    // K1: count3 || cvt || bpack0
    k1_kernel<<<FB + CVB + PB0, 256, 0, stream>>>(edst, etyp, cnt3, x, xb, W0, root0, Bpack0);

    // scans (cheap, dependent)
    scan1_kernel<<<(NN + 1023) / 1024, 1024, 0, stream>>>(cnt3, rowp, bsum);
    scan2_kernel<<<1, 128, 0, stream>>>(bsum, rowp);
    scan3_kernel<<<(NN + 255) / 256, 256, 0, stream>>>(rowp, cursor, bsum);

    // K5: fill || gemm0 || bpack1
    k5_kernel<<<FB + GB0 + PB1, 256, 0, stream>>>(esrc, edst, etyp, cursor, elist, xb,
                                                  Bpack0, trans, W1, root1, Bpack1);

    // layer 0 aggregate + finalize
    agg_finalize_kernel<0><<<NN / 4, 256, 0, stream>>>(trans, elist, rowp, cnt3, b0, g0, be0,
                                                       nullptr, nullptr, h1);

    // layer 1
    gemm1_kernel<<<GB0, 256, 0, stream>>>(h1, Bpack1, trans);
    agg_finalize_kernel<1><<<NN / 4, 256, 0, stream>>>(trans, elist, rowp, cnt3, b1, g1, be1,
                                                       gout, bout, d_out);
}